// Round 10
// baseline (132.567 us; speedup 1.0000x reference)
//
#include <hip/hip_runtime.h>
#include <hip/hip_bf16.h>

// GCN: out = GCNConv2( relu( GCNConv1(x) ) )
// Round 9->10:
//  - h1 stored in 3 slices of 32 dims (64B rows): slice s pinned to XCDs via
//    blockIdx%8 (slice = v%3, replica = v/3 owns a disjoint node range).
//    Per-XCD working set 3.2MB fits the 4MB L2 -> gather fetch 77->~26MB while
//    keeping dense-grade coalescing (1 line/row, 16 lines/wave-instr; round 8's
//    G=1 mistake had 64).
//  - GEMMs: LDS row padding (96->97 f32 / 98 u16) kills a 16-way bank conflict
//    on the x-read (row stride was 0 mod 32 banks); 64 rows/block, 4 rows/thread.

constexpr int NN = 50000;
constexpr int NE = 800000;
constexpr int DI = 96;
constexpr int DH = 96;
constexpr int DO = 48;

constexpr int BK_SHIFT = 6;                  // 64 dst nodes per bucket
constexpr int NBK      = (NN + 63) >> 6;     // 782 buckets
constexpr int BK_CAP   = 2048;

constexpr int NCHUNK = 256;                  // blocks in hist/scatter
constexpr int CH     = (NE + NCHUNK - 1) / NCHUNK;  // 3125

typedef unsigned short us8 __attribute__((ext_vector_type(8)));

__device__ __forceinline__ float bf2f(unsigned short u) {
    return __uint_as_float(((unsigned int)u) << 16);
}
__device__ __forceinline__ unsigned short f2bf(float f) {
    __hip_bfloat16 b = __float2bfloat16(f);
    return *reinterpret_cast<unsigned short*>(&b);
}

// ---------------- CSR build (atomic-free multisplit) ----------------

__global__ __launch_bounds__(256) void k_hist(const int* __restrict__ dst,
                                              int* __restrict__ C, int e) {
    __shared__ int hist[NBK];
    for (int i = threadIdx.x; i < NBK; i += 256) hist[i] = 0;
    __syncthreads();
    const int blk = blockIdx.x;
    const int beg = blk * CH, end = min(beg + CH, e);
    for (int i = beg + threadIdx.x; i < end; i += 256)
        atomicAdd(&hist[dst[i] >> BK_SHIFT], 1);
    __syncthreads();
    for (int b = threadIdx.x; b < NBK; b += 256)
        C[b * NCHUNK + blk] = hist[b];
}

__global__ __launch_bounds__(256) void k_rowscan(int* __restrict__ C,
                                                 int* __restrict__ totals,
                                                 int* __restrict__ row_ptr) {
    if (blockIdx.x == 0 && threadIdx.x == 0) row_ptr[NN] = NE;  // sentinel
    const int w    = threadIdx.x >> 6;
    const int lane = threadIdx.x & 63;
    const int r    = blockIdx.x * 4 + w;
    if (r >= NBK) return;
    int* row = C + r * NCHUNK;
    int v[4], s[4];
#pragma unroll
    for (int q = 0; q < 4; ++q) { v[q] = row[q * 64 + lane]; s[q] = v[q]; }
#pragma unroll
    for (int off = 1; off < 64; off <<= 1) {
#pragma unroll
        for (int q = 0; q < 4; ++q) {
            int y = __shfl_up(s[q], off);
            if (lane >= off) s[q] += y;
        }
    }
    int c0 = __shfl(s[0], 63);
    int c1 = __shfl(s[1], 63);
    int c2 = __shfl(s[2], 63);
    s[1] += c0;
    s[2] += c0 + c1;
    s[3] += c0 + c1 + c2;
#pragma unroll
    for (int q = 0; q < 4; ++q) row[q * 64 + lane] = s[q] - v[q];
    if (lane == 63) totals[r] = s[3];
}

__global__ __launch_bounds__(256) void k_scatter(const int* __restrict__ src,
                                                 const int* __restrict__ dst,
                                                 const int* __restrict__ C,
                                                 const int* __restrict__ totals,
                                                 int* __restrict__ bk_ptr,
                                                 unsigned* __restrict__ ebuf, int e) {
    __shared__ int bkL[NBK + 1];
    __shared__ int part[256];
    __shared__ int cur[NBK];
    const int t = threadIdx.x;

    int v[4];
    int s = 0;
    const int base = t * 4;
#pragma unroll
    for (int i = 0; i < 4; ++i) {
        int idx = base + i;
        v[i] = (idx < NBK) ? totals[idx] : 0;
        s += v[i];
    }
    part[t] = s;
    __syncthreads();
#pragma unroll
    for (int off = 1; off < 256; off <<= 1) {
        int x = part[t];
        int a = (t >= off) ? part[t - off] : 0;
        __syncthreads();
        part[t] = x + a;
        __syncthreads();
    }
    int run = part[t] - s;
#pragma unroll
    for (int i = 0; i < 4; ++i) {
        int idx = base + i;
        if (idx <= NBK) bkL[idx] = run;
        run += v[i];
    }
    __syncthreads();

    const int blk = blockIdx.x;
    for (int b = t; b < NBK; b += 256) cur[b] = bkL[b] + C[b * NCHUNK + blk];
    if (blk == 0)
        for (int i = t; i <= NBK; i += 256) bk_ptr[i] = bkL[i];
    __syncthreads();

    const int beg = blk * CH, end = min(beg + CH, e);
    for (int i = beg + t; i < end; i += 256) {
        int d = dst[i];
        int b = d >> BK_SHIFT;
        int pos = atomicAdd(&cur[b], 1);   // LDS atomic, short chains
        ebuf[pos] = ((unsigned)(d & 63) << 16) | (unsigned)src[i];  // NN < 65536
    }
}

__global__ __launch_bounds__(256) void k_bsort(const unsigned* __restrict__ ebuf,
                                               const int* __restrict__ bk_ptr,
                                               int* __restrict__ row_ptr,
                                               float* __restrict__ dinv,
                                               unsigned short* __restrict__ src16, int n) {
    __shared__ unsigned eL[BK_CAP];
    __shared__ unsigned short outL[BK_CAP];
    __shared__ int curL[64];
    __shared__ int baseL[64];

    const int b   = blockIdx.x;
    const int beg = bk_ptr[b];
    const int m   = bk_ptr[b + 1] - beg;
    const int t   = threadIdx.x;

    if (t < 64) curL[t] = 0;
    __syncthreads();

    for (int i = t; i < m; i += 256) {
        unsigned v = ebuf[beg + i];
        eL[i] = v;
        atomicAdd(&curL[v >> 16], 1);
    }
    __syncthreads();

    if (t < 64) {
        int c = curL[t];
        int x = c;
#pragma unroll
        for (int off = 1; off < 64; off <<= 1) {
            int y = __shfl_up(x, off);
            if (t >= off) x += y;
        }
        int excl = x - c;
        baseL[t] = excl;
        int d0 = (b << BK_SHIFT) + t;
        if (d0 < n) {
            row_ptr[d0] = beg + excl;
            dinv[d0]    = rsqrtf((float)(c + 1));   // +1 self-loop
        }
    }
    __syncthreads();
    if (t < 64) curL[t] = baseL[t];
    __syncthreads();

    for (int i = t; i < m; i += 256) {
        unsigned v = eL[i];
        int p = atomicAdd(&curL[v >> 16], 1);
        outL[p] = (unsigned short)(v & 0xFFFFu);
    }
    __syncthreads();
    for (int i = t; i < m; i += 256) src16[beg + i] = outL[i];
}

// ---------------- GEMM 1: Hsl[3][n][32] = bf16( dinv * (X f32 @ W1) ) ----------------
// 64 rows/block, 4 rows/thread; LDS rows padded to 97 f32 (2-way banks, was 16-way).

__global__ __launch_bounds__(256) void k_gemm1(const float* __restrict__ X,
                                               const float* __restrict__ W,
                                               const float* __restrict__ dinv,
                                               unsigned short* __restrict__ Hsl, int n) {
    constexpr int ROWS = 64, P = 97;
    __shared__ float ws[DI * DH];     // 36.9 KB
    __shared__ float xs[ROWS * P];    // 24.8 KB (aliased as hout after k-loop)
    unsigned short* hout = reinterpret_cast<unsigned short*>(xs);

    const int tid  = threadIdx.x;
    const int row0 = blockIdx.x * ROWS;

    for (int i = tid; i < DI * DH; i += 256) ws[i] = W[i];
    {
        const float4* Xv = reinterpret_cast<const float4*>(X + (size_t)row0 * DI);
        const int nv   = ROWS * DI / 4;                 // 1536
        const int maxv = ((n - row0) * DI) / 4;
        for (int i = tid; i < nv; i += 256) {
            float4 v = (i < maxv) ? Xv[i] : float4{0.f, 0.f, 0.f, 0.f};
            int r = i / 24, c = (i % 24) * 4;
            xs[r * P + c + 0] = v.x;
            xs[r * P + c + 1] = v.y;
            xs[r * P + c + 2] = v.z;
            xs[r * P + c + 3] = v.w;
        }
    }
    __syncthreads();

    const int cg = tid & 15, rg = tid >> 4;
    float acc[4][6] = {};
#pragma unroll 2
    for (int k = 0; k < DI; ++k) {
        float xv[4];
#pragma unroll
        for (int i = 0; i < 4; ++i) xv[i] = xs[(rg * 4 + i) * P + k];
#pragma unroll
        for (int j = 0; j < 6; ++j) {
            float wv = ws[k * DH + cg * 6 + j];
#pragma unroll
            for (int i = 0; i < 4; ++i) acc[i][j] += xv[i] * wv;
        }
    }
    __syncthreads();   // xs reads done

#pragma unroll
    for (int i = 0; i < 4; ++i) {
        int row = row0 + rg * 4 + i;
        float dv = (row < n) ? dinv[row] : 0.f;
#pragma unroll
        for (int j = 0; j < 6; ++j)
            hout[(rg * 4 + i) * 96 + cg * 6 + j] = f2bf(acc[i][j] * dv);
    }
    __syncthreads();

    // sliced write: 3 slices x 64 rows, 64B per (slice,row)
    if (tid < 192) {
        int s = tid >> 6, r = tid & 63;
        int row = row0 + r;
        if (row < n) {
            const us8* srcp = reinterpret_cast<const us8*>(hout + r * 96 + s * 32);
            us8* dstp = reinterpret_cast<us8*>(Hsl + ((size_t)s * n + row) * 32);
#pragma unroll
            for (int q = 0; q < 4; ++q) dstp[q] = srcp[q];
        }
    }
}

// ---------------- GEMM 2: H[n][48] = bf16( dinv * (A1 bf16 @ W2) ) ----------------

__global__ __launch_bounds__(256) void k_gemm2(const unsigned short* __restrict__ A,
                                               const float* __restrict__ W,
                                               const float* __restrict__ dinv,
                                               unsigned short* __restrict__ H, int n) {
    constexpr int ROWS = 64, P = 98;
    __shared__ float ws[DH * DO];           // 18.4 KB
    __shared__ unsigned short xs[ROWS * P]; // 12.5 KB

    const int tid  = threadIdx.x;
    const int row0 = blockIdx.x * ROWS;

    for (int i = tid; i < DH * DO; i += 256) ws[i] = W[i];
    {
        const us8* Av = reinterpret_cast<const us8*>(A + (size_t)row0 * DH);
        const int nv   = ROWS * DH / 8;                 // 768
        const int maxv = ((n - row0) * DH) / 8;
        for (int i = tid; i < nv; i += 256) {
            us8 v = (i < maxv) ? Av[i] : (us8)(0);
            int r = i / 12, c = (i % 12) * 8;
#pragma unroll
            for (int jj = 0; jj < 8; ++jj) xs[r * P + c + jj] = v[jj];
        }
    }
    __syncthreads();

    const int cg = tid & 15, rg = tid >> 4;
    float acc[4][3] = {};
#pragma unroll 2
    for (int k = 0; k < DH; ++k) {
        float xv[4];
#pragma unroll
        for (int i = 0; i < 4; ++i) xv[i] = bf2f(xs[(rg * 4 + i) * P + k]);
#pragma unroll
        for (int j = 0; j < 3; ++j) {
            float wv = ws[k * DO + cg * 3 + j];
#pragma unroll
            for (int i = 0; i < 4; ++i) acc[i][j] += xv[i] * wv;
        }
    }

#pragma unroll
    for (int i = 0; i < 4; ++i) {
        int row = row0 + rg * 4 + i;
        if (row < n) {
            float dv = dinv[row];
#pragma unroll
            for (int j = 0; j < 3; ++j)
                H[(size_t)row * DO + cg * 3 + j] = f2bf(acc[i][j] * dv);
        }
    }
}

// ---------------- layer-1 aggregation: 3-slice, XCD-pinned ----------------
// vslice v = blockIdx%8; real slice s = v%3 (dims [s*32,(s+1)*32)); replica v/3
// owns a disjoint node range. Per-XCD working set = one 3.2MB slice (L2-fits).
// G=4 lanes/node, 64B rows -> 1 line per gather, dense-grade coalescing.

__global__ __launch_bounds__(256) void k_agg_sl3(const unsigned short* __restrict__ hsl,
                                                 const float* __restrict__ dinv,
                                                 const int* __restrict__ row_ptr,
                                                 const unsigned short* __restrict__ src16,
                                                 const float* __restrict__ bias,
                                                 unsigned short* __restrict__ a1, int n) {
    const int v   = blockIdx.x & 7;
    const int s   = (v >= 6) ? (v - 6) : (v >= 3 ? v - 3 : v);   // v % 3
    const int rep = (v >= 6) ? 2 : (v >= 3 ? 1 : 0);             // v / 3
    const int R   = (s == 2) ? 2 : 3;
    const int cnt = (n + R - 1) / R;
    const int lo  = rep * cnt;
    const int hi  = min(lo + cnt, n);
    const int node = lo + ((int)(blockIdx.x >> 3) << 6) + ((int)threadIdx.x >> 2);
    if (node >= hi) return;
    const int g = threadIdx.x & 3;

    const us8* hs = reinterpret_cast<const us8*>(hsl + (size_t)s * n * 32);

    float accA[8], accB[8];
    {
        us8 hv = hs[(size_t)node * 4 + g];   // self term
#pragma unroll
        for (int j = 0; j < 8; ++j) { accA[j] = bf2f(hv[j]); accB[j] = 0.f; }
    }

    const int beg = row_ptr[node];
    const int end = row_ptr[node + 1];
    int k = beg;
    int kA = min((beg + 7) & ~7, end);
    for (; k < kA; ++k) {
        us8 vv = hs[(size_t)src16[k] * 4 + g];
#pragma unroll
        for (int j = 0; j < 8; ++j) accA[j] += bf2f(vv[j]);
    }
    for (; k + 8 <= end; k += 8) {
        us8 si = *reinterpret_cast<const us8*>(src16 + k);
        us8 v0 = hs[(size_t)si[0] * 4 + g];
        us8 v1 = hs[(size_t)si[1] * 4 + g];
        us8 v2 = hs[(size_t)si[2] * 4 + g];
        us8 v3 = hs[(size_t)si[3] * 4 + g];
        us8 v4 = hs[(size_t)si[4] * 4 + g];
        us8 v5 = hs[(size_t)si[5] * 4 + g];
        us8 v6 = hs[(size_t)si[6] * 4 + g];
        us8 v7 = hs[(size_t)si[7] * 4 + g];
#pragma unroll
        for (int j = 0; j < 8; ++j) {
            accA[j] += (bf2f(v0[j]) + bf2f(v1[j])) + (bf2f(v4[j]) + bf2f(v5[j]));
            accB[j] += (bf2f(v2[j]) + bf2f(v3[j])) + (bf2f(v6[j]) + bf2f(v7[j]));
        }
    }
    for (; k < end; ++k) {
        us8 vv = hs[(size_t)src16[k] * 4 + g];
#pragma unroll
        for (int j = 0; j < 8; ++j) accB[j] += bf2f(vv[j]);
    }

    const float di = dinv[node];
    const float4* b4 = reinterpret_cast<const float4*>(bias);
    float4 b0 = b4[s * 8 + g * 2], b1 = b4[s * 8 + g * 2 + 1];
    float r[8];
#pragma unroll
    for (int j = 0; j < 8; ++j) r[j] = di * (accA[j] + accB[j]);
    r[0] += b0.x; r[1] += b0.y; r[2] += b0.z; r[3] += b0.w;
    r[4] += b1.x; r[5] += b1.y; r[6] += b1.z; r[7] += b1.w;
    us8 o;
#pragma unroll
    for (int j = 0; j < 8; ++j) o[j] = f2bf(fmaxf(r[j], 0.f));   // relu
    *reinterpret_cast<us8*>(a1 + (size_t)node * DH + s * 32 + g * 8) = o;
}

// ---------------- layer-2 aggregation: dense (h2 = 4.8MB) ----------------

template<int D, bool RELU, bool OUTBF16>
__global__ __launch_bounds__(256) void k_agg_csr(const unsigned short* __restrict__ h,
                                                 const float* __restrict__ dinv,
                                                 const int* __restrict__ row_ptr,
                                                 const unsigned short* __restrict__ src16,
                                                 const float* __restrict__ bias,
                                                 void* __restrict__ outp, int n) {
    constexpr int G = D / 8;
    int t = blockIdx.x * blockDim.x + threadIdx.x;
    if (t >= n * G) return;
    const int node = t / G;
    const int g    = t % G;

    const us8* h8 = reinterpret_cast<const us8*>(h);

    float accA[8], accB[8];
    {
        us8 hv = h8[(size_t)node * G + g];
#pragma unroll
        for (int j = 0; j < 8; ++j) { accA[j] = bf2f(hv[j]); accB[j] = 0.f; }
    }

    const int beg = row_ptr[node];
    const int end = row_ptr[node + 1];
    int k = beg;
    int kA = min((beg + 7) & ~7, end);
    for (; k < kA; ++k) {
        us8 vv = h8[(size_t)src16[k] * G + g];
#pragma unroll
        for (int j = 0; j < 8; ++j) accA[j] += bf2f(vv[j]);
    }
    for (; k + 8 <= end; k += 8) {
        us8 si = *reinterpret_cast<const us8*>(src16 + k);
        us8 v0 = h8[(size_t)si[0] * G + g];
        us8 v1 = h8[(size_t)si[1] * G + g];
        us8 v2 = h8[(size_t)si[2] * G + g];
        us8 v3 = h8[(size_t)si[3] * G + g];
        us8 v4 = h8[(size_t)si[4] * G + g];
        us8 v5 = h8[(size_t)si[5] * G + g];
        us8 v6 = h8[(size_t)si[6] * G + g];
        us8 v7 = h8[(size_t)si[7] * G + g];
#pragma unroll
        for (int j = 0; j < 8; ++j) {
            accA[j] += (bf2f(v0[j]) + bf2f(v1[j])) + (bf2f(v4[j]) + bf2f(v5[j]));
            accB[j] += (bf2f(v2[j]) + bf2f(v3[j])) + (bf2f(v6[j]) + bf2f(v7[j]));
        }
    }
    for (; k < end; ++k) {
        us8 vv = h8[(size_t)src16[k] * G + g];
#pragma unroll
        for (int j = 0; j < 8; ++j) accB[j] += bf2f(vv[j]);
    }

    const float di = dinv[node];
    const float4* b4 = reinterpret_cast<const float4*>(bias);
    float4 b0 = b4[g * 2], b1 = b4[g * 2 + 1];
    float r[8];
#pragma unroll
    for (int j = 0; j < 8; ++j) r[j] = di * (accA[j] + accB[j]);
    r[0] += b0.x; r[1] += b0.y; r[2] += b0.z; r[3] += b0.w;
    r[4] += b1.x; r[5] += b1.y; r[6] += b1.z; r[7] += b1.w;
    if (RELU) {
#pragma unroll
        for (int j = 0; j < 8; ++j) r[j] = fmaxf(r[j], 0.f);
    }
    if (OUTBF16) {
        us8 o;
#pragma unroll
        for (int j = 0; j < 8; ++j) o[j] = f2bf(r[j]);
        reinterpret_cast<us8*>((unsigned short*)outp)[(size_t)node * G + g] = o;
    } else {
        float4* o4 = reinterpret_cast<float4*>((float*)outp + (size_t)node * D + g * 8);
        o4[0] = float4{r[0], r[1], r[2], r[3]};
        o4[1] = float4{r[4], r[5], r[6], r[7]};
    }
}

// ---------------- launch ----------------

extern "C" void kernel_launch(void* const* d_in, const int* in_sizes, int n_in,
                              void* d_out, int out_size, void* d_ws, size_t ws_size,
                              hipStream_t stream) {
    const float* x   = (const float*)d_in[0];
    const int*   ei  = (const int*)d_in[1];   // [2][NE] int32
    const float* W1  = (const float*)d_in[2];
    const float* b1  = (const float*)d_in[3];
    const float* W2  = (const float*)d_in[4];
    const float* b2  = (const float*)d_in[5];
    float*       out = (float*)d_out;

    const int* srcv = ei;
    const int* dstv = ei + NE;

    // workspace layout (16B alignment for vector arrays)
    char* p = (char*)d_ws;
    float*          dinv  = (float*)p;           p += (size_t)NN * 4;
    unsigned short* a1    = (unsigned short*)p;  p += (size_t)NN * DH * 2;       // bf16 dense
    unsigned short* h1sl  = (unsigned short*)p;  p += (size_t)3 * NN * 32 * 2;   // sliced; h2 reuses
    int*      row_ptr     = (int*)p;             p += (size_t)(NN + 16) * 4;
    unsigned short* src16 = (unsigned short*)p;  p += (size_t)NE * 2;
    unsigned* ebuf        = (unsigned*)p;        p += (size_t)NE * 4;
    int*      Cm          = (int*)p;             p += (size_t)NBK * NCHUNK * 4;
    int*      totals      = (int*)p;             p += (size_t)NBK * 4;
    int*      bk_ptr      = (int*)p;             p += (size_t)(NBK + 1) * 4;

    const int B = 256;

    // CSR build (no global atomics)
    k_hist<<<NCHUNK, B, 0, stream>>>(dstv, Cm, NE);
    k_rowscan<<<(NBK + 3) / 4, B, 0, stream>>>(Cm, totals, row_ptr);
    k_scatter<<<NCHUNK, B, 0, stream>>>(srcv, dstv, Cm, totals, bk_ptr, ebuf, NE);
    k_bsort<<<NBK, B, 0, stream>>>(ebuf, bk_ptr, row_ptr, dinv, src16, NN);

    // layer 1: h1sl = bf16(dinv*(x@W1)) sliced ; a1 = bf16(relu(agg + b1)) dense
    k_gemm1<<<(NN + 63) / 64, B, 0, stream>>>(x, W1, dinv, h1sl, NN);
    {
        const int NCH = ((NN + 1) / 2 + 63) / 64;   // 391 chunks (max replica = 25000 nodes)
        k_agg_sl3<<<NCH * 8, B, 0, stream>>>(h1sl, dinv, row_ptr, src16, b1, a1, NN);
    }

    // layer 2: h2 (dense, reuses h1sl buffer) ; out = agg + b2 (f32)
    unsigned short* h2 = h1sl;
    k_gemm2<<<(NN + 63) / 64, B, 0, stream>>>(a1, W2, dinv, h2, NN);
    {
        int total = NN * (DO / 8);
        k_agg_csr<DO, false, false><<<(total + B - 1) / B, B, 0, stream>>>(
            h2, dinv, row_ptr, src16, b2, out, NN);
    }
}

// Round 11
// 125.825 us; speedup vs baseline: 1.0536x; 1.0536x over previous
//
#include <hip/hip_runtime.h>
#include <hip/hip_bf16.h>

// GCN: out = GCNConv2( relu( GCNConv1(x) ) )
// Round 10->11: ATTRIBUTION ROUND.
//  - Aggregation: reverted to round-9 dense layout (3-slice XCD pinning thrashed:
//    slice+src16+write-allocate ~5MB > 4MB L2, plus 33% replica imbalance).
//  - GEMMs: keep round-10 fix — LDS rows padded to 97 f32 / 98 u16 (x-read was a
//    16-way bank conflict at stride 96: 96*r mod 32 == 0), 64 rows/block,
//    4 rows/thread, LDS-staged us8 epilogue (dense bf16 H).

constexpr int NN = 50000;
constexpr int NE = 800000;
constexpr int DI = 96;
constexpr int DH = 96;
constexpr int DO = 48;

constexpr int BK_SHIFT = 6;                  // 64 dst nodes per bucket
constexpr int NBK      = (NN + 63) >> 6;     // 782 buckets
constexpr int BK_CAP   = 2048;

constexpr int NCHUNK = 256;                  // blocks in hist/scatter
constexpr int CH     = (NE + NCHUNK - 1) / NCHUNK;  // 3125

typedef unsigned short us8 __attribute__((ext_vector_type(8)));

__device__ __forceinline__ float bf2f(unsigned short u) {
    return __uint_as_float(((unsigned int)u) << 16);
}
__device__ __forceinline__ unsigned short f2bf(float f) {
    __hip_bfloat16 b = __float2bfloat16(f);
    return *reinterpret_cast<unsigned short*>(&b);
}

// ---------------- CSR build (atomic-free multisplit) ----------------

__global__ __launch_bounds__(256) void k_hist(const int* __restrict__ dst,
                                              int* __restrict__ C, int e) {
    __shared__ int hist[NBK];
    for (int i = threadIdx.x; i < NBK; i += 256) hist[i] = 0;
    __syncthreads();
    const int blk = blockIdx.x;
    const int beg = blk * CH, end = min(beg + CH, e);
    for (int i = beg + threadIdx.x; i < end; i += 256)
        atomicAdd(&hist[dst[i] >> BK_SHIFT], 1);
    __syncthreads();
    for (int b = threadIdx.x; b < NBK; b += 256)
        C[b * NCHUNK + blk] = hist[b];
}

__global__ __launch_bounds__(256) void k_rowscan(int* __restrict__ C,
                                                 int* __restrict__ totals,
                                                 int* __restrict__ row_ptr) {
    if (blockIdx.x == 0 && threadIdx.x == 0) row_ptr[NN] = NE;  // sentinel
    const int w    = threadIdx.x >> 6;
    const int lane = threadIdx.x & 63;
    const int r    = blockIdx.x * 4 + w;
    if (r >= NBK) return;
    int* row = C + r * NCHUNK;
    int v[4], s[4];
#pragma unroll
    for (int q = 0; q < 4; ++q) { v[q] = row[q * 64 + lane]; s[q] = v[q]; }
#pragma unroll
    for (int off = 1; off < 64; off <<= 1) {
#pragma unroll
        for (int q = 0; q < 4; ++q) {
            int y = __shfl_up(s[q], off);
            if (lane >= off) s[q] += y;
        }
    }
    int c0 = __shfl(s[0], 63);
    int c1 = __shfl(s[1], 63);
    int c2 = __shfl(s[2], 63);
    s[1] += c0;
    s[2] += c0 + c1;
    s[3] += c0 + c1 + c2;
#pragma unroll
    for (int q = 0; q < 4; ++q) row[q * 64 + lane] = s[q] - v[q];
    if (lane == 63) totals[r] = s[3];
}

__global__ __launch_bounds__(256) void k_scatter(const int* __restrict__ src,
                                                 const int* __restrict__ dst,
                                                 const int* __restrict__ C,
                                                 const int* __restrict__ totals,
                                                 int* __restrict__ bk_ptr,
                                                 unsigned* __restrict__ ebuf, int e) {
    __shared__ int bkL[NBK + 1];
    __shared__ int part[256];
    __shared__ int cur[NBK];
    const int t = threadIdx.x;

    int v[4];
    int s = 0;
    const int base = t * 4;
#pragma unroll
    for (int i = 0; i < 4; ++i) {
        int idx = base + i;
        v[i] = (idx < NBK) ? totals[idx] : 0;
        s += v[i];
    }
    part[t] = s;
    __syncthreads();
#pragma unroll
    for (int off = 1; off < 256; off <<= 1) {
        int x = part[t];
        int a = (t >= off) ? part[t - off] : 0;
        __syncthreads();
        part[t] = x + a;
        __syncthreads();
    }
    int run = part[t] - s;
#pragma unroll
    for (int i = 0; i < 4; ++i) {
        int idx = base + i;
        if (idx <= NBK) bkL[idx] = run;
        run += v[i];
    }
    __syncthreads();

    const int blk = blockIdx.x;
    for (int b = t; b < NBK; b += 256) cur[b] = bkL[b] + C[b * NCHUNK + blk];
    if (blk == 0)
        for (int i = t; i <= NBK; i += 256) bk_ptr[i] = bkL[i];
    __syncthreads();

    const int beg = blk * CH, end = min(beg + CH, e);
    for (int i = beg + t; i < end; i += 256) {
        int d = dst[i];
        int b = d >> BK_SHIFT;
        int pos = atomicAdd(&cur[b], 1);   // LDS atomic, short chains
        ebuf[pos] = ((unsigned)(d & 63) << 16) | (unsigned)src[i];  // NN < 65536
    }
}

__global__ __launch_bounds__(256) void k_bsort(const unsigned* __restrict__ ebuf,
                                               const int* __restrict__ bk_ptr,
                                               int* __restrict__ row_ptr,
                                               float* __restrict__ dinv,
                                               unsigned short* __restrict__ src16, int n) {
    __shared__ unsigned eL[BK_CAP];
    __shared__ unsigned short outL[BK_CAP];
    __shared__ int curL[64];
    __shared__ int baseL[64];

    const int b   = blockIdx.x;
    const int beg = bk_ptr[b];
    const int m   = bk_ptr[b + 1] - beg;
    const int t   = threadIdx.x;

    if (t < 64) curL[t] = 0;
    __syncthreads();

    for (int i = t; i < m; i += 256) {
        unsigned v = ebuf[beg + i];
        eL[i] = v;
        atomicAdd(&curL[v >> 16], 1);
    }
    __syncthreads();

    if (t < 64) {
        int c = curL[t];
        int x = c;
#pragma unroll
        for (int off = 1; off < 64; off <<= 1) {
            int y = __shfl_up(x, off);
            if (t >= off) x += y;
        }
        int excl = x - c;
        baseL[t] = excl;
        int d0 = (b << BK_SHIFT) + t;
        if (d0 < n) {
            row_ptr[d0] = beg + excl;
            dinv[d0]    = rsqrtf((float)(c + 1));   // +1 self-loop
        }
    }
    __syncthreads();
    if (t < 64) curL[t] = baseL[t];
    __syncthreads();

    for (int i = t; i < m; i += 256) {
        unsigned v = eL[i];
        int p = atomicAdd(&curL[v >> 16], 1);
        outL[p] = (unsigned short)(v & 0xFFFFu);
    }
    __syncthreads();
    for (int i = t; i < m; i += 256) src16[beg + i] = outL[i];
}

// ---------------- GEMM 1: H[n][96] = bf16( dinv * (X f32 @ W1) ) ----------------
// 64 rows/block, 4 rows/thread; LDS x rows padded to 97 f32 (was 16-way bank conflict).

__global__ __launch_bounds__(256) void k_gemm1(const float* __restrict__ X,
                                               const float* __restrict__ W,
                                               const float* __restrict__ dinv,
                                               unsigned short* __restrict__ H, int n) {
    constexpr int ROWS = 64, P = 97;
    __shared__ float ws[DI * DH];     // 36.9 KB
    __shared__ float xs[ROWS * P];    // 24.8 KB (aliased as hout after k-loop)
    unsigned short* hout = reinterpret_cast<unsigned short*>(xs);

    const int tid  = threadIdx.x;
    const int row0 = blockIdx.x * ROWS;

    for (int i = tid; i < DI * DH; i += 256) ws[i] = W[i];
    {
        const float4* Xv = reinterpret_cast<const float4*>(X + (size_t)row0 * DI);
        const int nv   = ROWS * DI / 4;                 // 1536
        const int maxv = ((n - row0) * DI) / 4;
        for (int i = tid; i < nv; i += 256) {
            float4 v = (i < maxv) ? Xv[i] : float4{0.f, 0.f, 0.f, 0.f};
            int r = i / 24, c = (i % 24) * 4;
            xs[r * P + c + 0] = v.x;
            xs[r * P + c + 1] = v.y;
            xs[r * P + c + 2] = v.z;
            xs[r * P + c + 3] = v.w;
        }
    }
    __syncthreads();

    const int cg = tid & 15, rg = tid >> 4;
    float acc[4][6] = {};
#pragma unroll 2
    for (int k = 0; k < DI; ++k) {
        float xv[4];
#pragma unroll
        for (int i = 0; i < 4; ++i) xv[i] = xs[(rg * 4 + i) * P + k];
#pragma unroll
        for (int j = 0; j < 6; ++j) {
            float wv = ws[k * DH + cg * 6 + j];
#pragma unroll
            for (int i = 0; i < 4; ++i) acc[i][j] += xv[i] * wv;
        }
    }
    __syncthreads();   // xs reads done before aliasing

#pragma unroll
    for (int i = 0; i < 4; ++i) {
        int row = row0 + rg * 4 + i;
        float dv = (row < n) ? dinv[row] : 0.f;
#pragma unroll
        for (int j = 0; j < 6; ++j)
            hout[(rg * 4 + i) * 96 + cg * 6 + j] = f2bf(acc[i][j] * dv);
    }
    __syncthreads();

    // coalesced dense write: 64 rows x 96 u16 = 768 us8
    {
        const us8* ho8 = reinterpret_cast<const us8*>(hout);
        us8* H8 = reinterpret_cast<us8*>(H + (size_t)row0 * DH);
        const int nv   = ROWS * DH / 8;                 // 768
        const int maxv = ((n - row0) * DH) / 8;
        for (int i = tid; i < nv && i < maxv; i += 256) H8[i] = ho8[i];
    }
}

// ---------------- GEMM 2: H[n][48] = bf16( dinv * (A1 bf16 @ W2) ) ----------------

__global__ __launch_bounds__(256) void k_gemm2(const unsigned short* __restrict__ A,
                                               const float* __restrict__ W,
                                               const float* __restrict__ dinv,
                                               unsigned short* __restrict__ H, int n) {
    constexpr int ROWS = 64, P = 98;
    __shared__ float ws[DH * DO];           // 18.4 KB
    __shared__ unsigned short xs[ROWS * P]; // 12.5 KB (aliased as hout after k-loop)

    const int tid  = threadIdx.x;
    const int row0 = blockIdx.x * ROWS;

    for (int i = tid; i < DH * DO; i += 256) ws[i] = W[i];
    {
        const us8* Av = reinterpret_cast<const us8*>(A + (size_t)row0 * DH);
        const int nv   = ROWS * DH / 8;                 // 768
        const int maxv = ((n - row0) * DH) / 8;
        for (int i = tid; i < nv; i += 256) {
            us8 v = (i < maxv) ? Av[i] : (us8)(0);
            int r = i / 12, c = (i % 12) * 8;
#pragma unroll
            for (int jj = 0; jj < 8; ++jj) xs[r * P + c + jj] = v[jj];
        }
    }
    __syncthreads();

    const int cg = tid & 15, rg = tid >> 4;
    float acc[4][3] = {};
#pragma unroll 2
    for (int k = 0; k < DH; ++k) {
        float xv[4];
#pragma unroll
        for (int i = 0; i < 4; ++i) xv[i] = bf2f(xs[(rg * 4 + i) * P + k]);
#pragma unroll
        for (int j = 0; j < 3; ++j) {
            float wv = ws[k * DO + cg * 3 + j];
#pragma unroll
            for (int i = 0; i < 4; ++i) acc[i][j] += xv[i] * wv;
        }
    }
    __syncthreads();   // xs reads done before aliasing

    unsigned short* hout = xs;
#pragma unroll
    for (int i = 0; i < 4; ++i) {
        int row = row0 + rg * 4 + i;
        float dv = (row < n) ? dinv[row] : 0.f;
#pragma unroll
        for (int j = 0; j < 3; ++j)
            hout[(rg * 4 + i) * 48 + cg * 3 + j] = f2bf(acc[i][j] * dv);
    }
    __syncthreads();

    {
        const us8* ho8 = reinterpret_cast<const us8*>(hout);
        us8* H8 = reinterpret_cast<us8*>(H + (size_t)row0 * DO);
        const int nv   = ROWS * DO / 8;                 // 384
        const int maxv = ((n - row0) * DO) / 8;
        for (int i = tid; i < nv && i < maxv; i += 256) H8[i] = ho8[i];
    }
}

// ---------------- CSR aggregation over pre-scaled bf16 h' (dense layout) ----------------
// out[d] = dinv[d] * ( h'[d] + sum_{s in N(d)} h'[s] ) + bias ;  h' = dinv*h
// thread = (node, 8-dim group); 8-deep gather pipeline over u16 indices.

template<int D, bool RELU, bool OUTBF16>
__global__ __launch_bounds__(256) void k_agg_csr(const unsigned short* __restrict__ h,
                                                 const float* __restrict__ dinv,
                                                 const int* __restrict__ row_ptr,
                                                 const unsigned short* __restrict__ src16,
                                                 const float* __restrict__ bias,
                                                 void* __restrict__ outp, int n) {
    constexpr int G = D / 8;
    int t = blockIdx.x * blockDim.x + threadIdx.x;
    if (t >= n * G) return;
    const int node = t / G;
    const int g    = t % G;

    const us8* h8 = reinterpret_cast<const us8*>(h);

    float accA[8], accB[8];
    {
        us8 hv = h8[(size_t)node * G + g];   // self term h'[node]
#pragma unroll
        for (int j = 0; j < 8; ++j) { accA[j] = bf2f(hv[j]); accB[j] = 0.f; }
    }

    const int beg = row_ptr[node];
    const int end = row_ptr[node + 1];
    int k = beg;
    int kA = min((beg + 7) & ~7, end);
    for (; k < kA; ++k) {
        us8 vv = h8[(size_t)src16[k] * G + g];
#pragma unroll
        for (int j = 0; j < 8; ++j) accA[j] += bf2f(vv[j]);
    }
    for (; k + 8 <= end; k += 8) {
        us8 si = *reinterpret_cast<const us8*>(src16 + k);
        us8 v0 = h8[(size_t)si[0] * G + g];
        us8 v1 = h8[(size_t)si[1] * G + g];
        us8 v2 = h8[(size_t)si[2] * G + g];
        us8 v3 = h8[(size_t)si[3] * G + g];
        us8 v4 = h8[(size_t)si[4] * G + g];
        us8 v5 = h8[(size_t)si[5] * G + g];
        us8 v6 = h8[(size_t)si[6] * G + g];
        us8 v7 = h8[(size_t)si[7] * G + g];
#pragma unroll
        for (int j = 0; j < 8; ++j) {
            accA[j] += (bf2f(v0[j]) + bf2f(v1[j])) + (bf2f(v4[j]) + bf2f(v5[j]));
            accB[j] += (bf2f(v2[j]) + bf2f(v3[j])) + (bf2f(v6[j]) + bf2f(v7[j]));
        }
    }
    for (; k < end; ++k) {
        us8 vv = h8[(size_t)src16[k] * G + g];
#pragma unroll
        for (int j = 0; j < 8; ++j) accB[j] += bf2f(vv[j]);
    }

    const float di = dinv[node];
    const float4* b4 = reinterpret_cast<const float4*>(bias);
    float4 b0 = b4[g * 2], b1 = b4[g * 2 + 1];
    float r[8];
#pragma unroll
    for (int j = 0; j < 8; ++j) r[j] = di * (accA[j] + accB[j]);
    r[0] += b0.x; r[1] += b0.y; r[2] += b0.z; r[3] += b0.w;
    r[4] += b1.x; r[5] += b1.y; r[6] += b1.z; r[7] += b1.w;
    if (RELU) {
#pragma unroll
        for (int j = 0; j < 8; ++j) r[j] = fmaxf(r[j], 0.f);
    }
    if (OUTBF16) {
        us8 o;
#pragma unroll
        for (int j = 0; j < 8; ++j) o[j] = f2bf(r[j]);
        reinterpret_cast<us8*>((unsigned short*)outp)[(size_t)node * G + g] = o;
    } else {
        float4* o4 = reinterpret_cast<float4*>((float*)outp + (size_t)node * D + g * 8);
        o4[0] = float4{r[0], r[1], r[2], r[3]};
        o4[1] = float4{r[4], r[5], r[6], r[7]};
    }
}

// ---------------- launch ----------------

extern "C" void kernel_launch(void* const* d_in, const int* in_sizes, int n_in,
                              void* d_out, int out_size, void* d_ws, size_t ws_size,
                              hipStream_t stream) {
    const float* x   = (const float*)d_in[0];
    const int*   ei  = (const int*)d_in[1];   // [2][NE] int32
    const float* W1  = (const float*)d_in[2];
    const float* b1  = (const float*)d_in[3];
    const float* W2  = (const float*)d_in[4];
    const float* b2  = (const float*)d_in[5];
    float*       out = (float*)d_out;

    const int* srcv = ei;
    const int* dstv = ei + NE;

    // workspace layout (16B alignment for vector arrays)
    char* p = (char*)d_ws;
    float*          dinv  = (float*)p;           p += (size_t)NN * 4;
    unsigned short* a1    = (unsigned short*)p;  p += (size_t)NN * DH * 2;   // bf16
    unsigned short* h1    = (unsigned short*)p;  p += (size_t)NN * DH * 2;   // bf16, reused as h2
    int*      row_ptr     = (int*)p;             p += (size_t)(NN + 16) * 4;
    unsigned short* src16 = (unsigned short*)p;  p += (size_t)NE * 2;
    unsigned* ebuf        = (unsigned*)p;        p += (size_t)NE * 4;
    int*      Cm          = (int*)p;             p += (size_t)NBK * NCHUNK * 4;
    int*      totals      = (int*)p;             p += (size_t)NBK * 4;
    int*      bk_ptr      = (int*)p;             p += (size_t)(NBK + 1) * 4;

    const int B = 256;

    // CSR build (no global atomics)
    k_hist<<<NCHUNK, B, 0, stream>>>(dstv, Cm, NE);
    k_rowscan<<<(NBK + 3) / 4, B, 0, stream>>>(Cm, totals, row_ptr);
    k_scatter<<<NCHUNK, B, 0, stream>>>(srcv, dstv, Cm, totals, bk_ptr, ebuf, NE);
    k_bsort<<<NBK, B, 0, stream>>>(ebuf, bk_ptr, row_ptr, dinv, src16, NN);

    // layer 1: h1 = bf16(dinv * (x@W1)) ; a1 = bf16(relu(dinv*(self+gather) + b1))
    k_gemm1<<<(NN + 63) / 64, B, 0, stream>>>(x, W1, dinv, h1, NN);
    {
        int total = NN * (DH / 8);
        k_agg_csr<DH, true, true><<<(total + B - 1) / B, B, 0, stream>>>(
            h1, dinv, row_ptr, src16, b1, a1, NN);
    }

    // layer 2: h2 = bf16(dinv * (a1@W2)) ; out = dinv*(self+gather) + b2
    unsigned short* h2 = h1;
    k_gemm2<<<(NN + 63) / 64, B, 0, stream>>>(a1, W2, dinv, h2, NN);
    {
        int total = NN * (DO / 8);
        k_agg_csr<DO, false, false><<<(total + B - 1) / B, B, 0, stream>>>(
            h2, dinv, row_ptr, src16, b2, out, NN);
    }
}